// Round 7
// baseline (366.248 us; speedup 1.0000x reference)
//
#include <hip/hip_runtime.h>

typedef short bf16x8 __attribute__((ext_vector_type(8)));
typedef float f32x4 __attribute__((ext_vector_type(4)));
typedef unsigned uint4v __attribute__((ext_vector_type(4)));

#define NROWS 131072L
#define DIN 1024
#define DEMB 512
#define NEXT 640   // extended B rows: 512 emb + 34 folded-head + 94 zero

// f32 -> bf16 RNE bit-twiddle (one-time prep kernels).
__device__ __forceinline__ unsigned short f2bf(float f) {
  unsigned u = __float_as_uint(f);
  u += 0x7FFFu + ((u >> 16) & 1u);
  return (unsigned short)(u >> 16);
}

// Pack two f32 -> two bf16 (round-half-up): 2 adds + 1 v_perm_b32 (R5/R6-proven).
__device__ __forceinline__ unsigned pkhi(float a, float b) {
  unsigned ua = __float_as_uint(a) + 0x8000u;
  unsigned ub = __float_as_uint(b) + 0x8000u;
  return __builtin_amdgcn_perm(ub, ua, 0x07060302u);
}

__device__ __forceinline__ float softplusf(float v) {
  return fmaxf(v, 0.f) + log1pf(expf(-fabsf(v)));
}

// ---------- kernel 0: Wb (1024x512 f32) -> WbT rows 0..511 (bf16, k-contig) ----------
__global__ __launch_bounds__(256) void wb_transpose(const float* __restrict__ Wb,
                                                    unsigned short* __restrict__ WbT) {
  int g = blockIdx.x * 256 + threadIdx.x;
  int n = g & 511;
  int kb = g >> 9;
  unsigned short tmp[8];
#pragma unroll
  for (int j = 0; j < 8; ++j)
    tmp[j] = f2bf(Wb[(kb * 8 + j) * DEMB + n]);
  uint4 v;
  v.x = (unsigned)tmp[0] | ((unsigned)tmp[1] << 16);
  v.y = (unsigned)tmp[2] | ((unsigned)tmp[3] << 16);
  v.z = (unsigned)tmp[4] | ((unsigned)tmp[5] << 16);
  v.w = (unsigned)tmp[6] | ((unsigned)tmp[7] << 16);
  *(uint4*)(WbT + (long)n * DIN + kb * 8) = v;
}

// ---------- kernel 0b: zero rows 546..639 of WbT_ext ----------
__global__ void zero_tail(unsigned* __restrict__ p) {
  p[blockIdx.x * 256 + threadIdx.x] = 0u;
}

// ---------- kernel 0c: WbT rows 512..545 = (Wb @ W34)^T  (head-weight fold) ----------
__global__ __launch_bounds__(256) void wfold_rows(const float* __restrict__ Wb,
                                                  const float* __restrict__ Wp,
                                                  const float* __restrict__ Ws,
                                                  unsigned short* __restrict__ WbT) {
  int w = threadIdx.x >> 6, lane = threadIdx.x & 63;
  int k = blockIdx.x * 4 + w;
  if (lane >= 34) return;
  const float* src;
  if (lane < 2) src = Wp + lane;
  else { int s = (lane - 2) >> 1; src = Ws + s * 1024 + (lane & 1); }
  const float* wrow = Wb + (long)k * DEMB;
  float acc = 0.f;
#pragma unroll 8
  for (int d = 0; d < DEMB; ++d) acc = fmaf(wrow[d], src[2 * d], acc);
  WbT[(long)(512 + lane) * DIN + k] = f2bf(acc);
}

// ---------- kernel 0d: bfold[j] = bb @ W34[:,j] + bias34[j] ----------
__global__ void bfold_k(const float* __restrict__ bb, const float* __restrict__ Wp,
                        const float* __restrict__ bp, const float* __restrict__ Ws,
                        const float* __restrict__ bs, float* __restrict__ bf) {
  int j = threadIdx.x;
  if (j >= 34) return;
  const float* src; float bias;
  if (j < 2) { src = Wp + j; bias = bp[j]; }
  else { int s = (j - 2) >> 1; src = Ws + s * 1024 + (j & 1); bias = bs[s * 2 + (j & 1)]; }
  float acc = bias;
  for (int d = 0; d < DEMB; ++d) acc = fmaf(bb[d], src[2 * d], acc);
  bf[j] = acc;
}

// ---------- kernel 1: fused GEMM, drain-free pipeline ----------
// 128x128 tile, BK=32, 2x2 waves. A staged as f32 via global_load_lds into a
// 3-slot rotation (issue 2 tiles ahead); B bf16 2-slot (1 ahead). Counted
// vmcnt(4) at every barrier keeps A(t+2) in flight ACROSS two barriers —
// no vmcnt(0) drain in steady state, no A reg-round-trip, no ds_writes.
__global__ __launch_bounds__(256, 2) void gemm_fused(
    const float* __restrict__ x, const unsigned short* __restrict__ wbt,
    const float* __restrict__ bb, const int* __restrict__ sid,
    const float* __restrict__ bfold, float* __restrict__ out) {
  __shared__ __align__(16) char SM[65536];
  char* const A0 = SM;               // f32 A slots, 16 KiB each
  char* const A1 = SM + 16384;
  char* const A2 = SM + 32768;
  char* const B0 = SM + 49152;       // bf16 B slots, 8 KiB each
  char* const B1 = SM + 57344;

  const int t = threadIdx.x;
  const int lane = t & 63;
  const int wid = t >> 6;
  const int wm = wid >> 1, wn = wid & 1;

  // XCD swizzle: 5120 blocks (%8==0); 5 consecutive swz share mtile on one XCD.
  const int bid = blockIdx.x;
  const int swz = (bid & 7) * 640 + (bid >> 3);
  const int mtile = swz / 5;
  const int ntile = swz - mtile * 5;
  const long m0 = (long)mtile * 128;
  const int n0 = ntile * 128;

  // ---- A stage (f32, global_load_lds, pre-swizzled source) ----
  // LDS linear dest byte = p*4096 + t*16  ->  (row = p*32 + (t>>3), phys granule t&7)
  // phys granule g holds logical k-granule g ^ (row&7)  -> src granule = (t&7)^((t>>3)&7)
  const int gswA = (t & 7) ^ ((t >> 3) & 7);
  const float* xA = x + (m0 + (t >> 3)) * DIN + gswA * 4;

  // ---- B stage (bf16, global_load_lds, pre-swizzled source; R6-proven) ----
  const int bn = wid * 16 + (lane >> 2);
  const int bsg = (lane & 3) ^ ((lane >> 3) & 3);
  const unsigned short* bsrc = wbt + (long)(n0 + bn) * DIN + bsg * 8;

  // ---- fragment read offsets ----
  const int l15 = lane & 15, lg = lane >> 4;
  // B: granule = lg ^ ((l15>>1)&3), 64B rows (R4/R6-proven, conflict-free)
  const int kgoB = ((lg ^ ((l15 >> 1) & 3)) << 4);
  const int brdrow = (wn * 64 + l15) * 64;
  // A f32: 128B rows, two b128 granules per frag: phys (lg*2+j) ^ (l15&7)
  const int arow = (wm * 64 + l15) * 128;
  const int g0x = (((lg * 2) ^ (l15 & 7)) << 4);
  const int g1x = (((lg * 2 + 1) ^ (l15 & 7)) << 4);

  f32x4 acc[4][4] = {};

  auto stageA = [&](char* Aw, int k0) {
#pragma unroll
    for (int p = 0; p < 4; ++p) {
      const float* gp = xA + (long)p * 32 * DIN + k0;
      __builtin_amdgcn_global_load_lds(
          (const __attribute__((address_space(1))) void*)gp,
          (__attribute__((address_space(3))) void*)(Aw + p * 4096 + wid * 1024),
          16, 0, 0);
    }
  };
  auto stageB = [&](char* Bw, int k0) {
#pragma unroll
    for (int i = 0; i < 2; ++i) {
      const unsigned short* gp = bsrc + (long)i * 64 * DIN + k0;
      __builtin_amdgcn_global_load_lds(
          (const __attribute__((address_space(1))) void*)gp,
          (__attribute__((address_space(3))) void*)(Bw + i * 4096 + wid * 1024),
          16, 0, 0);
    }
  };
  auto compute = [&](const char* Ac, const char* Bc) {
    bf16x8 af[4], bfv[4];
#pragma unroll
    for (int i = 0; i < 4; ++i) {
      f32x4 q0 = *(const f32x4*)(Ac + arow + i * 2048 + g0x);
      f32x4 q1 = *(const f32x4*)(Ac + arow + i * 2048 + g1x);
      uint4v u;
      u[0] = pkhi(q0[0], q0[1]); u[1] = pkhi(q0[2], q0[3]);
      u[2] = pkhi(q1[0], q1[1]); u[3] = pkhi(q1[2], q1[3]);
      af[i] = __builtin_bit_cast(bf16x8, u);
      bfv[i] = *(const bf16x8*)(Bc + brdrow + i * 1024 + kgoB);
    }
#pragma unroll
    for (int mi = 0; mi < 4; ++mi)
#pragma unroll
      for (int ni = 0; ni < 4; ++ni)
        acc[mi][ni] = __builtin_amdgcn_mfma_f32_16x16x32_bf16(af[mi], bfv[ni],
                                                             acc[mi][ni], 0, 0, 0);
  };
  // body t: issue B(t+1), A(t+2); compute tile t; drain oldest 6 (A(t+1),B(t+1)),
  // keep A(t+2)'s 4 in flight across the barrier.
  auto body = [&](char* Ac, char* Aw, char* Bc, char* Bw, int tt) {
    stageB(Bw, (tt + 1) * 32);
    stageA(Aw, (tt + 2) * 32);
    compute(Ac, Bc);
    __builtin_amdgcn_sched_barrier(0);
    asm volatile("s_waitcnt vmcnt(4) lgkmcnt(0)" ::: "memory");
    __builtin_amdgcn_sched_barrier(0);
    __builtin_amdgcn_s_barrier();
  };

  // prologue: A(0),B(0) staged+drained; A(1) left in flight (FIFO: issued last)
  stageA(A0, 0);
  stageB(B0, 0);
  stageA(A1, 32);
  __builtin_amdgcn_sched_barrier(0);
  asm volatile("s_waitcnt vmcnt(4) lgkmcnt(0)" ::: "memory");
  __builtin_amdgcn_sched_barrier(0);
  __builtin_amdgcn_s_barrier();

#pragma unroll 1
  for (int tb = 0; tb < 30; tb += 6) {   // slot maps: A: t%3 / (t+2)%3 ; B: t&1 / (t+1)&1
    body(A0, A2, B0, B1, tb + 0);
    body(A1, A0, B1, B0, tb + 1);
    body(A2, A1, B0, B1, tb + 2);
    body(A0, A2, B1, B0, tb + 3);
    body(A1, A0, B0, B1, tb + 4);
    body(A2, A1, B1, B0, tb + 5);
  }
  // t = 30: stage B(31); compute tile30; full drain (A(31)+B(31))
  stageB(B1, 31 * 32);
  compute(A0, B0);
  __builtin_amdgcn_sched_barrier(0);
  asm volatile("s_waitcnt vmcnt(0) lgkmcnt(0)" ::: "memory");
  __builtin_amdgcn_sched_barrier(0);
  __builtin_amdgcn_s_barrier();
  // t = 31
  compute(A1, B1);

  // ---- epilogue ----
  if (ntile < 4) {
    const int colg = n0 + wn * 64 + l15;
    float bbv[4];
#pragma unroll
    for (int ni = 0; ni < 4; ++ni) bbv[ni] = bb[colg + ni * 16];
#pragma unroll
    for (int mi = 0; mi < 4; ++mi) {
      const long rbase = m0 + wm * 64 + mi * 16 + lg * 4;
#pragma unroll
      for (int ni = 0; ni < 4; ++ni)
#pragma unroll
        for (int r = 0; r < 4; ++r)
          out[(rbase + r) * DEMB + colg + ni * 16] = acc[mi][ni][r] + bbv[ni];
    }
  } else {
    // head tile: acc cols 0..33 are x@Wfold; gather selected cols per row via LDS
    __syncthreads();
    float* hl = (float*)SM;          // [128][49] f32 = 25 KiB (overlays A slots)
    if (wn == 0) {
#pragma unroll
      for (int ni = 0; ni < 3; ++ni)
#pragma unroll
        for (int mi = 0; mi < 4; ++mi)
#pragma unroll
          for (int r = 0; r < 4; ++r) {
            int row = wm * 64 + mi * 16 + lg * 4 + r;
            hl[row * 49 + l15 + ni * 16] = acc[mi][ni][r];
          }
    }
    __syncthreads();
    if (t < 128) {
      const long row = m0 + t;
      const int s = sid[row];
      const float v0 = hl[t * 49 + 0] + bfold[0];
      const float v1 = hl[t * 49 + 1] + bfold[1];
      const float v2 = hl[t * 49 + 2 + 2 * s] + bfold[2 + 2 * s];
      const float v3 = hl[t * 49 + 3 + 2 * s] + bfold[3 + 2 * s];
      float* hp = out + NROWS * DEMB;
      hp[row] = v0;
      hp[NROWS + row] = softplusf(v1) + 0.001f;
      hp[2 * NROWS + row] = v2;
      hp[3 * NROWS + row] = softplusf(v3) + 0.001f;
    }
  }
}

extern "C" void kernel_launch(void* const* d_in, const int* in_sizes, int n_in,
                              void* d_out, int out_size, void* d_ws, size_t ws_size,
                              hipStream_t stream) {
  const float* x  = (const float*)d_in[0];
  const int* sid  = (const int*)d_in[1];
  const float* Wb = (const float*)d_in[2];
  const float* bb = (const float*)d_in[3];
  const float* Wp = (const float*)d_in[4];
  const float* bp = (const float*)d_in[5];
  const float* Ws = (const float*)d_in[6];
  const float* bs = (const float*)d_in[7];
  float* out = (float*)d_out;
  unsigned short* WbT = (unsigned short*)d_ws;            // 640*1024 bf16 = 1.25 MiB
  float* bfoldp = (float*)(WbT + (long)NEXT * DIN);       // 34 f32

  wb_transpose<<<256, 256, 0, stream>>>(Wb, WbT);
  zero_tail<<<188, 256, 0, stream>>>((unsigned*)(WbT + 546 * DIN));
  wfold_rows<<<256, 256, 0, stream>>>(Wb, Wp, Ws, WbT);
  bfold_k<<<1, 64, 0, stream>>>(bb, Wp, bp, Ws, bs, bfoldp);
  gemm_fused<<<5120, 256, 0, stream>>>(x, WbT, bb, sid, bfoldp, out);
}